// Round 1
// baseline (1119.848 us; speedup 1.0000x reference)
//
#include <hip/hip_runtime.h>
#include <math.h>

#define NN 6000
#define EE 100000
#define ELL (EE + NN)   // edges + self loops for GAT

// ---- ordered-uint mapping for float atomicMax ----
__device__ __forceinline__ unsigned f2ou(float f){
  unsigned u = __float_as_uint(f);
  return (u & 0x80000000u) ? ~u : (u | 0x80000000u);
}
__device__ __forceinline__ float ou2f(unsigned u){
  return (u & 0x80000000u) ? __uint_as_float(u & 0x7FFFFFFFu) : __uint_as_float(~u);
}

// ---- RGCN layer 0 (x = I): W0[r] = sum_b comp0[r,b]*basis0[b]  [2,N,32] ----
__global__ void k_w0(const float* __restrict__ basis, const float* __restrict__ comp,
                     float* __restrict__ W0){
  int t = blockIdx.x*256 + threadIdx.x;
  if (t >= 2*NN*32) return;
  int r = t / (NN*32);
  int no = t - r*(NN*32);
  float acc = 0.f;
  #pragma unroll
  for (int b=0;b<4;b++) acc += comp[r*4+b] * basis[b*(NN*32)+no];
  W0[t] = acc;
}

// per-relation in-degree counts (shared by all 4 layers)
__global__ void k_count(const int* __restrict__ ei, const int* __restrict__ et,
                        float* __restrict__ cnt){
  int e = blockIdx.x*256 + threadIdx.x;
  if (e >= EE) return;
  int r = et[e]; int d = ei[EE + e];
  atomicAdd(&cnt[r*NN + d], 1.0f);
}

__global__ void k_agg0(const int* __restrict__ ei, const int* __restrict__ et,
                       const float* __restrict__ W0, float* __restrict__ agg){
  int t = blockIdx.x*256 + threadIdx.x;
  if (t >= EE*32) return;
  int e = t >> 5, o = t & 31;
  int r = et[e]; int s = ei[e]; int d = ei[EE+e];
  atomicAdd(&agg[(r*NN + d)*32 + o], W0[(r*NN + s)*32 + o]);
}

__global__ void k_combine0(const float* __restrict__ root, const float* __restrict__ rbias,
                           const float* __restrict__ agg, const float* __restrict__ cnt,
                           float* __restrict__ xout){
  int t = blockIdx.x*256 + threadIdx.x;
  if (t >= NN*32) return;
  int n = t >> 5, o = t & 31;
  float v = root[t] + rbias[o];
  #pragma unroll
  for (int r=0;r<2;r++)
    v += agg[(r*NN+n)*32+o] / fmaxf(cnt[r*NN+n], 1.0f);
  xout[t] = tanhf(v);
}

// ---- generic RGCN layer: Wcat = [root | W0 | W1]  (I x 3O) ----
__global__ void k_wcat(const float* __restrict__ basis, const float* __restrict__ comp,
                       const float* __restrict__ root, float* __restrict__ Wcat,
                       int I, int O){
  int t = blockIdx.x*256 + threadIdx.x;
  if (t >= I*3*O) return;
  int i = t / (3*O); int col = t - i*3*O;
  float v;
  if (col < O) {
    v = root[i*O + col];
  } else {
    int r = (col - O) / O; int o = col - O - r*O;
    v = 0.f;
    #pragma unroll
    for (int b=0;b<4;b++) v += comp[r*4+b]*basis[(b*I+i)*O + o];
  }
  Wcat[t] = v;
}

// H = x @ Wcat : [N, 3O]  (cols [0,O)=root term, [O,2O)=rel0, [2O,3O)=rel1)
__global__ void k_nodemm(const float* __restrict__ x, const float* __restrict__ Wcat,
                         float* __restrict__ H, int I, int O){
  int C = 3*O;
  int t = blockIdx.x*256 + threadIdx.x;
  if (t >= NN*C) return;
  int n = t / C; int c = t - n*C;
  float acc = 0.f;
  for (int i=0;i<I;i++) acc += x[n*I+i]*Wcat[i*C+c];
  H[t] = acc;
}

__global__ void k_aggL(const int* __restrict__ ei, const int* __restrict__ et,
                       const float* __restrict__ H, float* __restrict__ agg, int O){
  long long t = (long long)blockIdx.x*256 + threadIdx.x;
  if (t >= (long long)EE*O) return;
  int e = (int)(t / O); int o = (int)(t - (long long)e*O);
  int r = et[e]; int s = ei[e]; int d = ei[EE+e];
  atomicAdd(&agg[(r*NN + d)*O + o], H[s*3*O + O + r*O + o]);
}

__global__ void k_combineL(const float* __restrict__ H, const float* __restrict__ rbias,
                           const float* __restrict__ agg, const float* __restrict__ cnt,
                           float* __restrict__ xout, int O){
  int t = blockIdx.x*256 + threadIdx.x;
  if (t >= NN*O) return;
  int n = t / O; int o = t - n*O;
  float v = H[n*3*O + o] + rbias[o];
  #pragma unroll
  for (int r=0;r<2;r++)
    v += agg[(r*NN+n)*O+o] / fmaxf(cnt[r*NN+n], 1.0f);
  xout[t] = tanhf(v);
}

// ---- GAT ----
__global__ void k_gath(const float* __restrict__ x, const float* __restrict__ gw,
                       float* __restrict__ h){
  int t = blockIdx.x*256 + threadIdx.x;
  if (t >= NN*512) return;
  int n = t >> 9, c = t & 511;
  float acc = 0.f;
  #pragma unroll
  for (int i=0;i<32;i++) acc += x[n*32+i]*gw[i*512+c];
  h[t] = acc;
}

__global__ void k_scores(const float* __restrict__ h, const float* __restrict__ as_,
                         const float* __restrict__ ad_, float* __restrict__ asv,
                         float* __restrict__ adv){
  int n = blockIdx.x*4 + (threadIdx.x >> 6);
  int lane = threadIdx.x & 63;
  if (n >= NN) return;
  float sa=0.f, sd=0.f;
  #pragma unroll
  for (int k=0;k<8;k++){
    int c = lane + 64*k;
    float hv = h[n*512+c];
    sa += hv*as_[c]; sd += hv*ad_[c];
  }
  #pragma unroll
  for (int m=32;m>0;m>>=1){ sa += __shfl_xor(sa,m,64); sd += __shfl_xor(sd,m,64); }
  if (lane==0){ asv[n]=sa; adv[n]=sd; }
}

__device__ __forceinline__ void edge_sd(int j, const int* __restrict__ ei, int& s, int& d){
  if (j < EE){ s = ei[j]; d = ei[EE+j]; } else { s = d = j - EE; }
}

__global__ void k_amax(const int* __restrict__ ei, const float* __restrict__ asv,
                       const float* __restrict__ adv, unsigned* __restrict__ amax){
  int j = blockIdx.x*256 + threadIdx.x;
  if (j >= ELL) return;
  int s,d; edge_sd(j, ei, s, d);
  float a = asv[s] + adv[d];
  a = (a >= 0.f) ? a : 0.2f*a;
  atomicMax(&amax[d], f2ou(a));
}

__global__ void k_denom(const int* __restrict__ ei, const float* __restrict__ asv,
                        const float* __restrict__ adv, const unsigned* __restrict__ amax,
                        float* __restrict__ denom){
  int j = blockIdx.x*256 + threadIdx.x;
  if (j >= ELL) return;
  int s,d; edge_sd(j, ei, s, d);
  float a = asv[s] + adv[d];
  a = (a >= 0.f) ? a : 0.2f*a;
  float m = ou2f(amax[d]);
  atomicAdd(&denom[d], expf(a - m));
}

__global__ void k_coef(const int* __restrict__ ei, const float* __restrict__ asv,
                       const float* __restrict__ adv, const unsigned* __restrict__ amax,
                       const float* __restrict__ denom, float* __restrict__ coef){
  int j = blockIdx.x*256 + threadIdx.x;
  if (j >= ELL) return;
  int s,d; edge_sd(j, ei, s, d);
  float a = asv[s] + adv[d];
  a = (a >= 0.f) ? a : 0.2f*a;
  float m = ou2f(amax[d]);
  coef[j] = expf(a - m) / fmaxf(denom[d], 1e-16f);
}

__global__ void k_gagg(const int* __restrict__ ei, const float* __restrict__ coef,
                       const float* __restrict__ h, float* __restrict__ out){
  long long t = (long long)blockIdx.x*256 + threadIdx.x;
  if (t >= (long long)ELL*128) return;
  int j = (int)(t >> 7); int q = (int)(t & 127);
  int s,d; edge_sd(j, ei, s, d);
  float c = coef[j];
  const float4 hv = *(const float4*)&h[s*512 + q*4];
  float* o = &out[d*512 + q*4];
  atomicAdd(o+0, c*hv.x); atomicAdd(o+1, c*hv.y);
  atomicAdd(o+2, c*hv.z); atomicAdd(o+3, c*hv.w);
}

__global__ void k_gfin(float* __restrict__ gout, const float* __restrict__ bias){
  int t = blockIdx.x*256 + threadIdx.x;
  if (t >= NN*512) return;
  gout[t] = fmaxf(gout[t] + bias[t & 511], 0.f);
}

// ---- edge MLP: A = x@w1[:512], B = x@w1[512:]  (8 nodes per block) ----
__global__ void k_AB(const float* __restrict__ x5, const float* __restrict__ w1,
                     float* __restrict__ A, float* __restrict__ B){
  __shared__ float sx[8*512];
  int n0 = blockIdx.x*8;
  for (int c = threadIdx.x; c < 8*512; c += 256){
    int t = c >> 9, cc = c & 511;
    sx[c] = x5[(n0+t)*512 + cc];
  }
  __syncthreads();
  int j = threadIdx.x & 127;
  int half = threadIdx.x >> 7;  // 0 -> A, 1 -> B
  const float* w = w1 + half*512*128 + j;
  float acc[8] = {0,0,0,0,0,0,0,0};
  for (int c=0;c<512;c++){
    float wv = w[c*128];
    #pragma unroll
    for (int t=0;t<8;t++) acc[t] += wv * sx[t*512 + c];
  }
  float* dst = half ? B : A;
  #pragma unroll
  for (int t=0;t<8;t++) dst[(n0+t)*128 + j] = acc[t];
}

__global__ void k_edge(const int* __restrict__ ei, const float* __restrict__ A,
                       const float* __restrict__ B, const float* __restrict__ b1,
                       const float* __restrict__ w2, const float* __restrict__ b2,
                       float* __restrict__ out){
  int e = blockIdx.x*4 + (threadIdx.x >> 6);
  int lane = threadIdx.x & 63;
  if (e >= EE) return;
  int s = ei[e], d = ei[EE+e];
  float acc = 0.f;
  #pragma unroll
  for (int k=0;k<2;k++){
    int j = lane + 64*k;
    float hv = A[s*128+j] + B[d*128+j] + b1[j];
    hv = fmaxf(hv, 0.f);
    acc += hv * w2[j];
  }
  #pragma unroll
  for (int m=32;m>0;m>>=1) acc += __shfl_xor(acc,m,64);
  if (lane==0) out[e] = 1.f/(1.f + expf(-(acc + b2[0])));
}

extern "C" void kernel_launch(void* const* d_in, const int* in_sizes, int n_in,
                              void* d_out, int out_size, void* d_ws, size_t ws_size,
                              hipStream_t stream){
  const float* basis0 = (const float*)d_in[0];
  const float* comp0  = (const float*)d_in[1];
  const float* root0  = (const float*)d_in[2];
  const float* rbias0 = (const float*)d_in[3];
  const float* basisL[4] = {basis0,(const float*)d_in[4],(const float*)d_in[8],(const float*)d_in[12]};
  const float* compL[4]  = {comp0,(const float*)d_in[5],(const float*)d_in[9],(const float*)d_in[13]};
  const float* rootL[4]  = {root0,(const float*)d_in[6],(const float*)d_in[10],(const float*)d_in[14]};
  const float* rbiasL[4] = {rbias0,(const float*)d_in[7],(const float*)d_in[11],(const float*)d_in[15]};
  const float* gat_w = (const float*)d_in[16];
  const float* a_src = (const float*)d_in[17];
  const float* a_dst = (const float*)d_in[18];
  const float* gat_b = (const float*)d_in[19];
  const float* w1 = (const float*)d_in[20];
  const float* b1 = (const float*)d_in[21];
  const float* w2 = (const float*)d_in[22];
  const float* b2 = (const float*)d_in[23];
  const int* ei = (const int*)d_in[24];
  const int* et = (const int*)d_in[25];
  float* out = (float*)d_out;

  // workspace carve-up (floats)
  float* p = (float*)d_ws;
  float* cnt  = p; p += 2*NN;
  float* W0   = p; p += 2*NN*32;
  float* xa   = p; p += NN*64;
  float* xb   = p; p += NN*64;
  float* Wcat = p; p += 64*192;
  float* H    = p; p += NN*192;
  float* agg  = p; p += 2*NN*64;
  float* h    = p; p += NN*512;
  float* asv  = p; p += NN;
  float* adv  = p; p += NN;
  unsigned* amax = (unsigned*)p; p += NN;
  float* denom = p; p += NN;
  float* coef  = p; p += ELL;
  float* gout  = p; p += NN*512;
  float* A = p; p += NN*128;
  float* B = p; p += NN*128;

  auto grid = [](long long n){ return dim3((unsigned)((n + 255)/256)); };

  // ---- RGCN layer 0 (x = I) ----
  hipMemsetAsync(cnt, 0, 2*NN*sizeof(float), stream);
  k_w0<<<grid(2LL*NN*32),256,0,stream>>>(basis0, comp0, W0);
  k_count<<<grid(EE),256,0,stream>>>(ei, et, cnt);
  hipMemsetAsync(agg, 0, (size_t)2*NN*32*sizeof(float), stream);
  k_agg0<<<grid((long long)EE*32),256,0,stream>>>(ei, et, W0, agg);
  k_combine0<<<grid(NN*32),256,0,stream>>>(root0, rbias0, agg, cnt, xa);

  // ---- RGCN layers 1..3 ----
  int Is[4] = {NN,32,64,64}, Os[4] = {32,64,64,32};
  float* xin = xa; float* xout = xb;
  for (int l=1;l<4;l++){
    int I=Is[l], O=Os[l];
    k_wcat<<<grid(I*3*O),256,0,stream>>>(basisL[l], compL[l], rootL[l], Wcat, I, O);
    k_nodemm<<<grid((long long)NN*3*O),256,0,stream>>>(xin, Wcat, H, I, O);
    hipMemsetAsync(agg, 0, (size_t)2*NN*O*sizeof(float), stream);
    k_aggL<<<grid((long long)EE*O),256,0,stream>>>(ei, et, H, agg, O);
    k_combineL<<<grid((long long)NN*O),256,0,stream>>>(H, rbiasL[l], agg, cnt, xout, O);
    float* tmp = xin; xin = xout; xout = tmp;
  }
  // final RGCN output (N x 32) is in xin

  // ---- GAT ----
  k_gath<<<grid((long long)NN*512),256,0,stream>>>(xin, gat_w, h);
  k_scores<<<dim3((NN+3)/4),256,0,stream>>>(h, a_src, a_dst, asv, adv);
  hipMemsetAsync(amax, 0, NN*sizeof(unsigned), stream);
  hipMemsetAsync(denom, 0, NN*sizeof(float), stream);
  k_amax<<<grid(ELL),256,0,stream>>>(ei, asv, adv, amax);
  k_denom<<<grid(ELL),256,0,stream>>>(ei, asv, adv, amax, denom);
  k_coef<<<grid(ELL),256,0,stream>>>(ei, asv, adv, amax, denom, coef);
  hipMemsetAsync(gout, 0, (size_t)NN*512*sizeof(float), stream);
  k_gagg<<<grid((long long)ELL*128),256,0,stream>>>(ei, coef, h, gout);
  k_gfin<<<grid((long long)NN*512),256,0,stream>>>(gout, gat_b);

  // ---- edge MLP ----
  k_AB<<<dim3(NN/8),256,0,stream>>>(gout, w1, A, B);
  k_edge<<<dim3((EE+3)/4),256,0,stream>>>(ei, A, B, b1, w2, b2, out);
}

// Round 2
// 437.285 us; speedup vs baseline: 2.5609x; 2.5609x over previous
//
#include <hip/hip_runtime.h>
#include <math.h>

#define NN 6000
#define EE 100000
#define ELL (EE + NN)   // edges + self loops for GAT

// ---------------- CSR build (dst-sorted, includes GAT self-loops) -------------
__device__ __forceinline__ int dst_of(int j, const int* __restrict__ ei){
  return (j < EE) ? ei[EE + j] : (j - EE);
}

__global__ void k_deg(const int* __restrict__ ei, int* __restrict__ deg){
  int j = blockIdx.x*256 + threadIdx.x;
  if (j >= ELL) return;
  atomicAdd(&deg[dst_of(j, ei)], 1);
}

// single-block exclusive scan over NN=6000 (256 threads x 24 elements)
__global__ void k_scan(const int* __restrict__ deg, int* __restrict__ rowptr,
                       int* __restrict__ cursor){
  __shared__ int ssum[256];
  const int PER = 24; // 256*24 = 6144 >= 6000
  int tid = threadIdx.x;
  int base = tid*PER;
  int local[PER];
  int s = 0;
  #pragma unroll
  for (int k=0;k<PER;k++){ int i = base+k; int v = (i<NN)?deg[i]:0; local[k]=s; s+=v; }
  ssum[tid] = s; __syncthreads();
  for (int off=1; off<256; off<<=1){
    int v = (tid>=off) ? ssum[tid-off] : 0;
    __syncthreads();
    ssum[tid] += v;
    __syncthreads();
  }
  int prefix = (tid==0) ? 0 : ssum[tid-1];
  #pragma unroll
  for (int k=0;k<PER;k++){
    int i = base+k;
    if (i<NN){ int v = prefix+local[k]; rowptr[i]=v; cursor[i]=v; }
  }
  if (tid==255) rowptr[NN] = ssum[255];
}

__global__ void k_fill(const int* __restrict__ ei, int* __restrict__ cursor,
                       int* __restrict__ eids){
  int j = blockIdx.x*256 + threadIdx.x;
  if (j >= ELL) return;
  int d = dst_of(j, ei);
  int pos = atomicAdd(&cursor[d], 1);
  eids[pos] = j;
}

// per-relation in-degree counts (shared by all 4 RGCN layers)
__global__ void k_count(const int* __restrict__ ei, const int* __restrict__ et,
                        float* __restrict__ cnt){
  int e = blockIdx.x*256 + threadIdx.x;
  if (e >= EE) return;
  int r = et[e]; int d = ei[EE + e];
  atomicAdd(&cnt[r*NN + d], 1.0f);
}

// ---- RGCN layer 0 (x = I): W0[r] = sum_b comp0[r,b]*basis0[b]  [2,N,32] ----
__global__ void k_w0(const float* __restrict__ basis, const float* __restrict__ comp,
                     float* __restrict__ W0){
  int t = blockIdx.x*256 + threadIdx.x;
  if (t >= 2*NN*32) return;
  int r = t / (NN*32);
  int no = t - r*(NN*32);
  float acc = 0.f;
  #pragma unroll
  for (int b=0;b<4;b++) acc += comp[r*4+b] * basis[b*(NN*32)+no];
  W0[t] = acc;
}

// fused layer-0 aggregation + combine + tanh (gather via CSR, skip self-loops)
__global__ void k_ragg0(const float* __restrict__ W0, const float* __restrict__ root,
                        const float* __restrict__ rbias,
                        const int* __restrict__ rowptr, const int* __restrict__ eids,
                        const int* __restrict__ ei, const int* __restrict__ et,
                        const float* __restrict__ cnt, float* __restrict__ xout){
  int n = blockIdx.x*8 + (threadIdx.x >> 5);
  int o = threadIdx.x & 31;
  if (n >= NN) return;
  int r0 = rowptr[n], r1 = rowptr[n+1];
  float a0 = 0.f, a1 = 0.f;
  for (int j=r0;j<r1;j++){
    int jj = eids[j];
    if (jj >= EE) continue;          // self-loop: GAT only
    int s = ei[jj]; int r = et[jj];
    float v = W0[(r*NN + s)*32 + o];
    if (r==0) a0 += v; else a1 += v;
  }
  float v = root[n*32+o] + rbias[o]
          + a0/fmaxf(cnt[n],1.f) + a1/fmaxf(cnt[NN+n],1.f);
  xout[n*32+o] = tanhf(v);
}

// ---- generic RGCN layer: Wcat = [root | W0 | W1]  (I x 3O) ----
__global__ void k_wcat(const float* __restrict__ basis, const float* __restrict__ comp,
                       const float* __restrict__ root, float* __restrict__ Wcat,
                       int I, int O){
  int t = blockIdx.x*256 + threadIdx.x;
  if (t >= I*3*O) return;
  int i = t / (3*O); int col = t - i*3*O;
  float v;
  if (col < O) {
    v = root[i*O + col];
  } else {
    int r = (col - O) / O; int o = col - O - r*O;
    v = 0.f;
    #pragma unroll
    for (int b=0;b<4;b++) v += comp[r*4+b]*basis[(b*I+i)*O + o];
  }
  Wcat[t] = v;
}

// H = x @ Wcat : [N, 3O]  (cols [0,O)=root term, [O,2O)=rel0, [2O,3O)=rel1)
__global__ void k_nodemm(const float* __restrict__ x, const float* __restrict__ Wcat,
                         float* __restrict__ H, int I, int O){
  int C = 3*O;
  int t = blockIdx.x*256 + threadIdx.x;
  if (t >= NN*C) return;
  int n = t / C; int c = t - n*C;
  float acc = 0.f;
  for (int i=0;i<I;i++) acc += x[n*I+i]*Wcat[i*C+c];
  H[t] = acc;
}

// fused RGCN agg + mean + root + tanh for layers 1..3
template<int O>
__global__ void k_ragg(const float* __restrict__ H, const float* __restrict__ rbias,
                       const int* __restrict__ rowptr, const int* __restrict__ eids,
                       const int* __restrict__ ei, const int* __restrict__ et,
                       const float* __restrict__ cnt, float* __restrict__ xout){
  constexpr int NPB = 256/O;
  int n = blockIdx.x*NPB + threadIdx.x/O;
  int o = threadIdx.x % O;
  if (n >= NN) return;
  int r0 = rowptr[n], r1 = rowptr[n+1];
  float a0 = 0.f, a1 = 0.f;
  for (int j=r0;j<r1;j++){
    int jj = eids[j];
    if (jj >= EE) continue;
    int s = ei[jj]; int r = et[jj];
    float v = H[s*3*O + O + r*O + o];
    if (r==0) a0 += v; else a1 += v;
  }
  float v = H[n*3*O + o] + rbias[o]
          + a0/fmaxf(cnt[n],1.f) + a1/fmaxf(cnt[NN+n],1.f);
  xout[n*O+o] = tanhf(v);
}

// ---- GAT ----
__global__ void k_gath(const float* __restrict__ x, const float* __restrict__ gw,
                       float* __restrict__ h){
  int t = blockIdx.x*256 + threadIdx.x;
  if (t >= NN*512) return;
  int n = t >> 9, c = t & 511;
  float acc = 0.f;
  #pragma unroll
  for (int i=0;i<32;i++) acc += x[n*32+i]*gw[i*512+c];
  h[t] = acc;
}

__global__ void k_scores(const float* __restrict__ h, const float* __restrict__ as_,
                         const float* __restrict__ ad_, float* __restrict__ asv,
                         float* __restrict__ adv){
  int n = blockIdx.x*4 + (threadIdx.x >> 6);
  int lane = threadIdx.x & 63;
  if (n >= NN) return;
  float sa=0.f, sd=0.f;
  #pragma unroll
  for (int k=0;k<8;k++){
    int c = lane + 64*k;
    float hv = h[n*512+c];
    sa += hv*as_[c]; sd += hv*ad_[c];
  }
  #pragma unroll
  for (int m=32;m>0;m>>=1){ sa += __shfl_xor(sa,m,64); sd += __shfl_xor(sd,m,64); }
  if (lane==0){ asv[n]=sa; adv[n]=sd; }
}

// fused per-node softmax over incident edges; coef stored by CSR slot
__global__ void k_gat_soft(const int* __restrict__ rowptr, const int* __restrict__ eids,
                           const int* __restrict__ ei, const float* __restrict__ asv,
                           const float* __restrict__ adv, float* __restrict__ coef){
  int n = blockIdx.x*4 + (threadIdx.x >> 6);
  int lane = threadIdx.x & 63;
  if (n >= NN) return;
  int r0 = rowptr[n], r1 = rowptr[n+1];
  float advn = adv[n];
  float m = -1e30f;
  for (int j=r0+lane; j<r1; j+=64){
    int jj = eids[j]; int s = (jj<EE)? ei[jj] : jj-EE;
    float a = asv[s] + advn; a = (a>=0.f)? a : 0.2f*a;
    m = fmaxf(m, a);
  }
  #pragma unroll
  for (int off=32;off>0;off>>=1) m = fmaxf(m, __shfl_xor(m,off,64));
  float sum = 0.f;
  for (int j=r0+lane; j<r1; j+=64){
    int jj = eids[j]; int s = (jj<EE)? ei[jj] : jj-EE;
    float a = asv[s] + advn; a = (a>=0.f)? a : 0.2f*a;
    sum += expf(a - m);
  }
  #pragma unroll
  for (int off=32;off>0;off>>=1) sum += __shfl_xor(sum,off,64);
  float inv = 1.f / fmaxf(sum, 1e-16f);
  for (int j=r0+lane; j<r1; j+=64){
    int jj = eids[j]; int s = (jj<EE)? ei[jj] : jj-EE;
    float a = asv[s] + advn; a = (a>=0.f)? a : 0.2f*a;
    coef[j] = expf(a - m) * inv;
  }
}

// per-node gather aggregation + bias + relu (replaces k_gagg + k_gfin)
__global__ void k_gat_agg(const int* __restrict__ rowptr, const int* __restrict__ eids,
                          const int* __restrict__ ei, const float* __restrict__ coef,
                          const float* __restrict__ h, const float* __restrict__ bias,
                          float* __restrict__ gout){
  int n = blockIdx.x;
  int c = threadIdx.x;             // 128 threads * float4 = 512 channels
  int r0 = rowptr[n], r1 = rowptr[n+1];
  float4 acc = {0.f,0.f,0.f,0.f};
  for (int j=r0;j<r1;j++){
    int jj = eids[j]; int s = (jj<EE)? ei[jj] : jj-EE;
    float cf = coef[j];
    const float4 hv = *(const float4*)&h[s*512 + c*4];
    acc.x += cf*hv.x; acc.y += cf*hv.y; acc.z += cf*hv.z; acc.w += cf*hv.w;
  }
  const float4 b = *(const float4*)&bias[c*4];
  float4 o;
  o.x = fmaxf(acc.x+b.x, 0.f); o.y = fmaxf(acc.y+b.y, 0.f);
  o.z = fmaxf(acc.z+b.z, 0.f); o.w = fmaxf(acc.w+b.w, 0.f);
  *(float4*)&gout[n*512 + c*4] = o;
}

// ---- edge MLP: A = x@w1[:512], B = x@w1[512:]  (8 nodes per block) ----
__global__ void k_AB(const float* __restrict__ x5, const float* __restrict__ w1,
                     float* __restrict__ A, float* __restrict__ B){
  __shared__ float sx[8*512];
  int n0 = blockIdx.x*8;
  for (int c = threadIdx.x; c < 8*512; c += 256){
    int t = c >> 9, cc = c & 511;
    sx[c] = x5[(n0+t)*512 + cc];
  }
  __syncthreads();
  int j = threadIdx.x & 127;
  int half = threadIdx.x >> 7;  // 0 -> A, 1 -> B
  const float* w = w1 + half*512*128 + j;
  float acc[8] = {0,0,0,0,0,0,0,0};
  for (int c=0;c<512;c++){
    float wv = w[c*128];
    #pragma unroll
    for (int t=0;t<8;t++) acc[t] += wv * sx[t*512 + c];
  }
  float* dst = half ? B : A;
  #pragma unroll
  for (int t=0;t<8;t++) dst[(n0+t)*128 + j] = acc[t];
}

__global__ void k_edge(const int* __restrict__ ei, const float* __restrict__ A,
                       const float* __restrict__ B, const float* __restrict__ b1,
                       const float* __restrict__ w2, const float* __restrict__ b2,
                       float* __restrict__ out){
  int e = blockIdx.x*4 + (threadIdx.x >> 6);
  int lane = threadIdx.x & 63;
  if (e >= EE) return;
  int s = ei[e], d = ei[EE+e];
  float acc = 0.f;
  #pragma unroll
  for (int k=0;k<2;k++){
    int j = lane + 64*k;
    float hv = A[s*128+j] + B[d*128+j] + b1[j];
    hv = fmaxf(hv, 0.f);
    acc += hv * w2[j];
  }
  #pragma unroll
  for (int m=32;m>0;m>>=1) acc += __shfl_xor(acc,m,64);
  if (lane==0) out[e] = 1.f/(1.f + expf(-(acc + b2[0])));
}

extern "C" void kernel_launch(void* const* d_in, const int* in_sizes, int n_in,
                              void* d_out, int out_size, void* d_ws, size_t ws_size,
                              hipStream_t stream){
  const float* basis0 = (const float*)d_in[0];
  const float* comp0  = (const float*)d_in[1];
  const float* root0  = (const float*)d_in[2];
  const float* rbias0 = (const float*)d_in[3];
  const float* basisL[4] = {basis0,(const float*)d_in[4],(const float*)d_in[8],(const float*)d_in[12]};
  const float* compL[4]  = {comp0,(const float*)d_in[5],(const float*)d_in[9],(const float*)d_in[13]};
  const float* rootL[4]  = {root0,(const float*)d_in[6],(const float*)d_in[10],(const float*)d_in[14]};
  const float* rbiasL[4] = {rbias0,(const float*)d_in[7],(const float*)d_in[11],(const float*)d_in[15]};
  const float* gat_w = (const float*)d_in[16];
  const float* a_src = (const float*)d_in[17];
  const float* a_dst = (const float*)d_in[18];
  const float* gat_b = (const float*)d_in[19];
  const float* w1 = (const float*)d_in[20];
  const float* b1 = (const float*)d_in[21];
  const float* w2 = (const float*)d_in[22];
  const float* b2 = (const float*)d_in[23];
  const int* ei = (const int*)d_in[24];
  const int* et = (const int*)d_in[25];
  float* out = (float*)d_out;

  // workspace carve-up
  float* p = (float*)d_ws;
  float* cnt  = p; p += 2*NN;
  float* W0   = p; p += 2*NN*32;
  float* xa   = p; p += NN*64;
  float* xb   = p; p += NN*64;
  float* Wcat = p; p += 64*192;
  float* H    = p; p += NN*192;
  float* h    = p; p += NN*512;
  float* asv  = p; p += NN;
  float* adv  = p; p += NN;
  float* coef = p; p += ELL;
  float* gout = p; p += NN*512;
  float* A    = p; p += NN*128;
  float* B    = p; p += NN*128;
  int* deg    = (int*)p; p += NN;
  int* rowptr = (int*)p; p += NN+1;
  int* cursor = (int*)p; p += NN;
  int* eids   = (int*)p; p += ELL;

  auto grid = [](long long n){ return dim3((unsigned)((n + 255)/256)); };

  // ---- CSR build ----
  hipMemsetAsync(deg, 0, NN*sizeof(int), stream);
  k_deg<<<grid(ELL),256,0,stream>>>(ei, deg);
  k_scan<<<1,256,0,stream>>>(deg, rowptr, cursor);
  k_fill<<<grid(ELL),256,0,stream>>>(ei, cursor, eids);
  hipMemsetAsync(cnt, 0, 2*NN*sizeof(float), stream);
  k_count<<<grid(EE),256,0,stream>>>(ei, et, cnt);

  // ---- RGCN layer 0 (x = I) ----
  k_w0<<<grid(2LL*NN*32),256,0,stream>>>(basis0, comp0, W0);
  k_ragg0<<<dim3((NN+7)/8),256,0,stream>>>(W0, root0, rbias0, rowptr, eids, ei, et, cnt, xa);

  // ---- RGCN layers 1..3 ----
  int Is[4] = {NN,32,64,64}, Os[4] = {32,64,64,32};
  float* xin = xa; float* xout = xb;
  for (int l=1;l<4;l++){
    int I=Is[l], O=Os[l];
    k_wcat<<<grid(I*3*O),256,0,stream>>>(basisL[l], compL[l], rootL[l], Wcat, I, O);
    k_nodemm<<<grid((long long)NN*3*O),256,0,stream>>>(xin, Wcat, H, I, O);
    if (O == 64)
      k_ragg<64><<<dim3((NN+3)/4),256,0,stream>>>(H, rbiasL[l], rowptr, eids, ei, et, cnt, xout);
    else
      k_ragg<32><<<dim3((NN+7)/8),256,0,stream>>>(H, rbiasL[l], rowptr, eids, ei, et, cnt, xout);
    float* tmp = xin; xin = xout; xout = tmp;
  }
  // final RGCN output (N x 32) in xin

  // ---- GAT ----
  k_gath<<<grid((long long)NN*512),256,0,stream>>>(xin, gat_w, h);
  k_scores<<<dim3((NN+3)/4),256,0,stream>>>(h, a_src, a_dst, asv, adv);
  k_gat_soft<<<dim3((NN+3)/4),256,0,stream>>>(rowptr, eids, ei, asv, adv, coef);
  k_gat_agg<<<dim3(NN),128,0,stream>>>(rowptr, eids, ei, coef, h, gat_b, gout);

  // ---- edge MLP ----
  k_AB<<<dim3(NN/8),256,0,stream>>>(gout, w1, A, B);
  k_edge<<<dim3((EE+3)/4),256,0,stream>>>(ei, A, B, b1, w2, b2, out);
}

// Round 3
// 424.113 us; speedup vs baseline: 2.6404x; 1.0311x over previous
//
#include <hip/hip_runtime.h>
#include <math.h>

#define NN 6000
#define EE 100000
#define ELL (EE + NN)   // edges + self loops for GAT

// ---------------- CSR build (dst-sorted, includes GAT self-loops) -------------
__device__ __forceinline__ int dst_of(int j, const int* __restrict__ ei){
  return (j < EE) ? ei[EE + j] : (j - EE);
}

// fused degree + per-relation count (cnt immediately follows deg in ws; one memset)
__global__ void k_degcnt(const int* __restrict__ ei, const int* __restrict__ et,
                         int* __restrict__ deg, float* __restrict__ cnt){
  int j = blockIdx.x*256 + threadIdx.x;
  if (j >= ELL) return;
  if (j < EE){
    int d = ei[EE+j]; int r = et[j];
    atomicAdd(&deg[d], 1);
    atomicAdd(&cnt[r*NN+d], 1.0f);
  } else {
    atomicAdd(&deg[j-EE], 1);
  }
}

// single-block exclusive scan over NN=6000 (256 threads x 24 elements)
__global__ void k_scan(const int* __restrict__ deg, int* __restrict__ rowptr,
                       int* __restrict__ cursor){
  __shared__ int ssum[256];
  const int PER = 24; // 256*24 = 6144 >= 6000
  int tid = threadIdx.x;
  int base = tid*PER;
  int local[PER];
  int s = 0;
  #pragma unroll
  for (int k=0;k<PER;k++){ int i = base+k; int v = (i<NN)?deg[i]:0; local[k]=s; s+=v; }
  ssum[tid] = s; __syncthreads();
  for (int off=1; off<256; off<<=1){
    int v = (tid>=off) ? ssum[tid-off] : 0;
    __syncthreads();
    ssum[tid] += v;
    __syncthreads();
  }
  int prefix = (tid==0) ? 0 : ssum[tid-1];
  #pragma unroll
  for (int k=0;k<PER;k++){
    int i = base+k;
    if (i<NN){ int v = prefix+local[k]; rowptr[i]=v; cursor[i]=v; }
  }
  if (tid==255) rowptr[NN] = ssum[255];
}

__global__ void k_fill(const int* __restrict__ ei, int* __restrict__ cursor,
                       int* __restrict__ eids){
  int j = blockIdx.x*256 + threadIdx.x;
  if (j >= ELL) return;
  int d = dst_of(j, ei);
  int pos = atomicAdd(&cursor[d], 1);
  eids[pos] = j;
}

// ---- RGCN layer 0 (x = I): W0[r] = sum_b comp0[r,b]*basis0[b]  [2,N,32] ----
__global__ void k_w0(const float* __restrict__ basis, const float* __restrict__ comp,
                     float* __restrict__ W0){
  int t = blockIdx.x*256 + threadIdx.x;
  if (t >= 2*NN*32) return;
  int r = t / (NN*32);
  int no = t - r*(NN*32);
  float acc = 0.f;
  #pragma unroll
  for (int b=0;b<4;b++) acc += comp[r*4+b] * basis[b*(NN*32)+no];
  W0[t] = acc;
}

// all three layers' Wcat = [root | W0 | W1] in one kernel
// layout: L1 (32x192) @0, L2 (64x192) @6144, L3 (64x96) @18432; total 24576
__global__ void k_wcat_all(const float* __restrict__ b1,const float* __restrict__ c1,const float* __restrict__ r1,
                           const float* __restrict__ b2,const float* __restrict__ c2,const float* __restrict__ r2,
                           const float* __restrict__ b3,const float* __restrict__ c3,const float* __restrict__ r3,
                           float* __restrict__ Wcat){
  int t0 = blockIdx.x*256 + threadIdx.x;
  if (t0 >= 24576) return;
  const float *bb,*cc,*rr; int I,O; int t = t0;
  if (t0 < 6144)        { bb=b1;cc=c1;rr=r1;I=32;O=64; }
  else if (t0 < 18432)  { bb=b2;cc=c2;rr=r2;I=64;O=64; t -= 6144; }
  else                  { bb=b3;cc=c3;rr=r3;I=64;O=32; t -= 18432; }
  int C = 3*O;
  int i = t / C; int col = t - i*C;
  float v;
  if (col < O) {
    v = rr[i*O + col];
  } else {
    int r = (col - O) / O; int o = col - O - r*O;
    v = 0.f;
    #pragma unroll
    for (int b=0;b<4;b++) v += cc[r*4+b]*bb[(b*I+i)*O + o];
  }
  Wcat[t0] = v;
}

// fused layer-0 aggregation + combine + tanh (gather via CSR, skip self-loops)
__global__ void k_ragg0(const float* __restrict__ W0, const float* __restrict__ root,
                        const float* __restrict__ rbias,
                        const int* __restrict__ rowptr, const int* __restrict__ eids,
                        const int* __restrict__ ei, const int* __restrict__ et,
                        const float* __restrict__ cnt, float* __restrict__ xout){
  int n = blockIdx.x*8 + (threadIdx.x >> 5);
  int o = threadIdx.x & 31;
  if (n >= NN) return;
  int r0 = rowptr[n], r1 = rowptr[n+1];
  float a0 = 0.f, a1 = 0.f;
  for (int j=r0;j<r1;j++){
    int jj = eids[j];
    if (jj >= EE) continue;          // self-loop: GAT only
    int s = ei[jj]; int r = et[jj];
    float v = W0[(r*NN + s)*32 + o];
    if (r==0) a0 += v; else a1 += v;
  }
  float v = root[n*32+o] + rbias[o]
          + a0/fmaxf(cnt[n],1.f) + a1/fmaxf(cnt[NN+n],1.f);
  xout[n*32+o] = tanhf(v);
}

// H = x @ Wcat : [N, 3O]  (cols [0,O)=root term, [O,2O)=rel0, [2O,3O)=rel1)
__global__ void k_nodemm(const float* __restrict__ x, const float* __restrict__ Wcat,
                         float* __restrict__ H, int I, int O){
  int C = 3*O;
  int t = blockIdx.x*256 + threadIdx.x;
  if (t >= NN*C) return;
  int n = t / C; int c = t - n*C;
  float acc = 0.f;
  for (int i=0;i<I;i++) acc += x[n*I+i]*Wcat[i*C+c];
  H[t] = acc;
}

// fused RGCN agg + mean + root + tanh for layers 1..3
template<int O>
__global__ void k_ragg(const float* __restrict__ H, const float* __restrict__ rbias,
                       const int* __restrict__ rowptr, const int* __restrict__ eids,
                       const int* __restrict__ ei, const int* __restrict__ et,
                       const float* __restrict__ cnt, float* __restrict__ xout){
  constexpr int NPB = 256/O;
  int n = blockIdx.x*NPB + threadIdx.x/O;
  int o = threadIdx.x % O;
  if (n >= NN) return;
  int r0 = rowptr[n], r1 = rowptr[n+1];
  float a0 = 0.f, a1 = 0.f;
  for (int j=r0;j<r1;j++){
    int jj = eids[j];
    if (jj >= EE) continue;
    int s = ei[jj]; int r = et[jj];
    float v = H[s*3*O + O + r*O + o];
    if (r==0) a0 += v; else a1 += v;
  }
  float v = H[n*3*O + o] + rbias[o]
          + a0/fmaxf(cnt[n],1.f) + a1/fmaxf(cnt[NN+n],1.f);
  xout[n*O+o] = tanhf(v);
}

// ---- GAT: h = x@gw (4 nodes/block, gw reuse) fused with per-node scores ----
__global__ void k_gat(const float* __restrict__ x, const float* __restrict__ gw,
                      const float* __restrict__ as_, const float* __restrict__ ad_,
                      float* __restrict__ h, float* __restrict__ asv, float* __restrict__ adv){
  int n0 = blockIdx.x*4;
  int t = threadIdx.x;  // 128 threads: t*4 covers 512 channels
  __shared__ float sx[4*32];
  __shared__ float red[2][8];
  if (t < 128) { if (t < 4*32) sx[t] = x[n0*32 + t]; }
  __syncthreads();
  float4 acc[4] = {{0,0,0,0},{0,0,0,0},{0,0,0,0},{0,0,0,0}};
  for (int i=0;i<32;i++){
    const float4 g = *(const float4*)&gw[i*512 + t*4];
    #pragma unroll
    for (int k=0;k<4;k++){
      float xv = sx[k*32+i];
      acc[k].x += xv*g.x; acc[k].y += xv*g.y; acc[k].z += xv*g.z; acc[k].w += xv*g.w;
    }
  }
  const float4 a4 = *(const float4*)&as_[t*4];
  const float4 d4 = *(const float4*)&ad_[t*4];
  float sa[4], sd[4];
  #pragma unroll
  for (int k=0;k<4;k++){
    *(float4*)&h[(n0+k)*512 + t*4] = acc[k];
    sa[k] = acc[k].x*a4.x + acc[k].y*a4.y + acc[k].z*a4.z + acc[k].w*a4.w;
    sd[k] = acc[k].x*d4.x + acc[k].y*d4.y + acc[k].z*d4.z + acc[k].w*d4.w;
  }
  #pragma unroll
  for (int m=32;m>0;m>>=1){
    #pragma unroll
    for (int k=0;k<4;k++){ sa[k] += __shfl_xor(sa[k],m,64); sd[k] += __shfl_xor(sd[k],m,64); }
  }
  int wv = t>>6;
  if ((t&63)==0){
    #pragma unroll
    for (int k=0;k<4;k++){ red[wv][k]=sa[k]; red[wv][4+k]=sd[k]; }
  }
  __syncthreads();
  if (t<4){ asv[n0+t]=red[0][t]+red[1][t]; adv[n0+t]=red[0][4+t]+red[1][4+t]; }
}

// fused per-node softmax over incident edges; coef stored by CSR slot
__global__ void k_gat_soft(const int* __restrict__ rowptr, const int* __restrict__ eids,
                           const int* __restrict__ ei, const float* __restrict__ asv,
                           const float* __restrict__ adv, float* __restrict__ coef){
  int n = blockIdx.x*4 + (threadIdx.x >> 6);
  int lane = threadIdx.x & 63;
  if (n >= NN) return;
  int r0 = rowptr[n], r1 = rowptr[n+1];
  float advn = adv[n];
  float m = -1e30f;
  for (int j=r0+lane; j<r1; j+=64){
    int jj = eids[j]; int s = (jj<EE)? ei[jj] : jj-EE;
    float a = asv[s] + advn; a = (a>=0.f)? a : 0.2f*a;
    m = fmaxf(m, a);
  }
  #pragma unroll
  for (int off=32;off>0;off>>=1) m = fmaxf(m, __shfl_xor(m,off,64));
  float sum = 0.f;
  for (int j=r0+lane; j<r1; j+=64){
    int jj = eids[j]; int s = (jj<EE)? ei[jj] : jj-EE;
    float a = asv[s] + advn; a = (a>=0.f)? a : 0.2f*a;
    sum += expf(a - m);
  }
  #pragma unroll
  for (int off=32;off>0;off>>=1) sum += __shfl_xor(sum,off,64);
  float inv = 1.f / fmaxf(sum, 1e-16f);
  for (int j=r0+lane; j<r1; j+=64){
    int jj = eids[j]; int s = (jj<EE)? ei[jj] : jj-EE;
    float a = asv[s] + advn; a = (a>=0.f)? a : 0.2f*a;
    coef[j] = expf(a - m) * inv;
  }
}

// per-node gather aggregation + bias + relu
__global__ void k_gat_agg(const int* __restrict__ rowptr, const int* __restrict__ eids,
                          const int* __restrict__ ei, const float* __restrict__ coef,
                          const float* __restrict__ h, const float* __restrict__ bias,
                          float* __restrict__ gout){
  int n = blockIdx.x;
  int c = threadIdx.x;             // 128 threads * float4 = 512 channels
  int r0 = rowptr[n], r1 = rowptr[n+1];
  float4 acc = {0.f,0.f,0.f,0.f};
  for (int j=r0;j<r1;j++){
    int jj = eids[j]; int s = (jj<EE)? ei[jj] : jj-EE;
    float cf = coef[j];
    const float4 hv = *(const float4*)&h[s*512 + c*4];
    acc.x += cf*hv.x; acc.y += cf*hv.y; acc.z += cf*hv.z; acc.w += cf*hv.w;
  }
  const float4 b = *(const float4*)&bias[c*4];
  float4 o;
  o.x = fmaxf(acc.x+b.x, 0.f); o.y = fmaxf(acc.y+b.y, 0.f);
  o.z = fmaxf(acc.z+b.z, 0.f); o.w = fmaxf(acc.w+b.w, 0.f);
  *(float4*)&gout[n*512 + c*4] = o;
}

// ---- edge MLP precompute: A = x@w1[:512], B = x@w1[512:]  (8 nodes/block) ----
// thread owns (half, jlo/jhi, 4 nodes): ds:FMA = 1:8
__global__ void k_AB(const float* __restrict__ x5, const float* __restrict__ w1,
                     float* __restrict__ A, float* __restrict__ B){
  __shared__ float sx[8*512];
  int n0 = blockIdx.x*8;
  {
    const float4* src = (const float4*)(x5 + (size_t)n0*512);
    float4* dst = (float4*)sx;
    for (int c = threadIdx.x; c < 8*512/4; c += 256) dst[c] = src[c];
  }
  __syncthreads();
  int j     = threadIdx.x & 63;
  int half  = (threadIdx.x >> 6) & 1;   // 0 -> A, 1 -> B
  int tbase = (threadIdx.x >> 7) * 4;   // nodes [tbase, tbase+4)
  const float* wj = w1 + half*512*128 + j;
  float acc[8] = {0,0,0,0,0,0,0,0};
  for (int c4=0;c4<128;c4++){
    const float* wc = wj + c4*4*128;
    float wa0 = wc[0],   wb0 = wc[64];
    float wa1 = wc[128], wb1 = wc[192];
    float wa2 = wc[256], wb2 = wc[320];
    float wa3 = wc[384], wb3 = wc[448];
    #pragma unroll
    for (int tt=0;tt<4;tt++){
      const float4 xv = *(const float4*)&sx[(tbase+tt)*512 + c4*4];
      acc[tt*2]   += xv.x*wa0 + xv.y*wa1 + xv.z*wa2 + xv.w*wa3;
      acc[tt*2+1] += xv.x*wb0 + xv.y*wb1 + xv.z*wb2 + xv.w*wb3;
    }
  }
  float* dst = half ? B : A;
  #pragma unroll
  for (int tt=0;tt<4;tt++){
    dst[(n0+tbase+tt)*128 + j]      = acc[tt*2];
    dst[(n0+tbase+tt)*128 + j + 64] = acc[tt*2+1];
  }
}

__global__ void k_edge(const int* __restrict__ ei, const float* __restrict__ A,
                       const float* __restrict__ B, const float* __restrict__ b1,
                       const float* __restrict__ w2, const float* __restrict__ b2,
                       float* __restrict__ out){
  int e = blockIdx.x*4 + (threadIdx.x >> 6);
  int lane = threadIdx.x & 63;
  if (e >= EE) return;
  int s = ei[e], d = ei[EE+e];
  const float2 av = *(const float2*)&A[s*128 + lane*2];
  const float2 bv = *(const float2*)&B[d*128 + lane*2];
  const float2 b1v = *(const float2*)&b1[lane*2];
  const float2 w2v = *(const float2*)&w2[lane*2];
  float h0 = fmaxf(av.x + bv.x + b1v.x, 0.f);
  float h1 = fmaxf(av.y + bv.y + b1v.y, 0.f);
  float acc = h0*w2v.x + h1*w2v.y;
  #pragma unroll
  for (int m=32;m>0;m>>=1) acc += __shfl_xor(acc,m,64);
  if (lane==0) out[e] = 1.f/(1.f + expf(-(acc + b2[0])));
}

extern "C" void kernel_launch(void* const* d_in, const int* in_sizes, int n_in,
                              void* d_out, int out_size, void* d_ws, size_t ws_size,
                              hipStream_t stream){
  const float* basis0 = (const float*)d_in[0];
  const float* comp0  = (const float*)d_in[1];
  const float* root0  = (const float*)d_in[2];
  const float* rbias0 = (const float*)d_in[3];
  const float* basisL[4] = {basis0,(const float*)d_in[4],(const float*)d_in[8],(const float*)d_in[12]};
  const float* compL[4]  = {comp0,(const float*)d_in[5],(const float*)d_in[9],(const float*)d_in[13]};
  const float* rootL[4]  = {root0,(const float*)d_in[6],(const float*)d_in[10],(const float*)d_in[14]};
  const float* rbiasL[4] = {rbias0,(const float*)d_in[7],(const float*)d_in[11],(const float*)d_in[15]};
  const float* gat_w = (const float*)d_in[16];
  const float* a_src = (const float*)d_in[17];
  const float* a_dst = (const float*)d_in[18];
  const float* gat_b = (const float*)d_in[19];
  const float* w1 = (const float*)d_in[20];
  const float* b1 = (const float*)d_in[21];
  const float* w2 = (const float*)d_in[22];
  const float* b2 = (const float*)d_in[23];
  const int* ei = (const int*)d_in[24];
  const int* et = (const int*)d_in[25];
  float* out = (float*)d_out;

  // workspace carve-up (deg+cnt adjacent: one memset)
  float* p = (float*)d_ws;
  int* deg    = (int*)p; p += NN;
  float* cnt  = p; p += 2*NN;
  int* rowptr = (int*)p; p += NN+1;
  int* cursor = (int*)p; p += NN;
  int* eids   = (int*)p; p += ELL;
  float* W0   = p; p += 2*NN*32;
  float* Wcat = p; p += 24576;
  float* xa   = p; p += NN*64;
  float* xb   = p; p += NN*64;
  float* H    = p; p += NN*192;
  float* h    = p; p += NN*512;
  float* asv  = p; p += NN;
  float* adv  = p; p += NN;
  float* coef = p; p += ELL;
  float* gout = p; p += NN*512;
  float* A    = p; p += NN*128;
  float* B    = p; p += NN*128;

  auto grid = [](long long n){ return dim3((unsigned)((n + 255)/256)); };

  // ---- weight prep (independent of graph) ----
  k_w0<<<grid(2LL*NN*32),256,0,stream>>>(basis0, comp0, W0);
  k_wcat_all<<<grid(24576),256,0,stream>>>(basisL[1],compL[1],rootL[1],
                                           basisL[2],compL[2],rootL[2],
                                           basisL[3],compL[3],rootL[3], Wcat);

  // ---- CSR build ----
  hipMemsetAsync(deg, 0, (size_t)3*NN*sizeof(int), stream);  // deg + cnt
  k_degcnt<<<grid(ELL),256,0,stream>>>(ei, et, deg, cnt);
  k_scan<<<1,256,0,stream>>>(deg, rowptr, cursor);
  k_fill<<<grid(ELL),256,0,stream>>>(ei, cursor, eids);

  // ---- RGCN layer 0 (x = I) ----
  k_ragg0<<<dim3((NN+7)/8),256,0,stream>>>(W0, root0, rbias0, rowptr, eids, ei, et, cnt, xa);

  // ---- RGCN layers 1..3 ----
  int Is[4] = {NN,32,64,64}, Os[4] = {32,64,64,32};
  int WcatOff[4] = {0, 0, 6144, 18432};
  float* xin = xa; float* xout = xb;
  for (int l=1;l<4;l++){
    int I=Is[l], O=Os[l];
    k_nodemm<<<grid((long long)NN*3*O),256,0,stream>>>(xin, Wcat + WcatOff[l], H, I, O);
    if (O == 64)
      k_ragg<64><<<dim3((NN+3)/4),256,0,stream>>>(H, rbiasL[l], rowptr, eids, ei, et, cnt, xout);
    else
      k_ragg<32><<<dim3((NN+7)/8),256,0,stream>>>(H, rbiasL[l], rowptr, eids, ei, et, cnt, xout);
    float* tmp = xin; xin = xout; xout = tmp;
  }
  // final RGCN output (N x 32) in xin

  // ---- GAT ----
  k_gat<<<dim3(NN/4),128,0,stream>>>(xin, gat_w, a_src, a_dst, h, asv, adv);
  k_gat_soft<<<dim3((NN+3)/4),256,0,stream>>>(rowptr, eids, ei, asv, adv, coef);
  k_gat_agg<<<dim3(NN),128,0,stream>>>(rowptr, eids, ei, coef, h, gat_b, gout);

  // ---- edge MLP ----
  k_AB<<<dim3(NN/8),256,0,stream>>>(gout, w1, A, B);
  k_edge<<<dim3((EE+3)/4),256,0,stream>>>(ei, A, B, b1, w2, b2, out);
}